// Round 1
// baseline (161.493 us; speedup 1.0000x reference)
//
#include <hip/hip_runtime.h>
#include <hip/hip_bf16.h>
#include <cstdint>

// adknnLoss: N=8192 samples, M=128 features.
//   A = L*X; B = (X@Wnet + bnet)*X
//   dist[i,j] = ||A_i - B_j||;  drum = exp(-dist)
//   pred = (drum@Y)/drum.sum(1);  loss = sum((Y-pred)^2)
//
// Strategy: bf16 MFMA for the 8192x8192x128 Gram matrix (A@B^T), fused
// flash-style with the exp/row-reduction epilogue (S never materialized).
// Norms are computed from the bf16-rounded vectors so d2 = ||a-b||^2 is
// consistent (non-negative up to fp32 accumulation noise).

#define N_ 8192
#define M_ 128

typedef __bf16 bf16x8 __attribute__((ext_vector_type(8)));
typedef float  f32x4  __attribute__((ext_vector_type(4)));

__device__ __forceinline__ unsigned short f2bf(float f) {
    // round-to-nearest-even fp32 -> bf16
    unsigned int x = __float_as_uint(f);
    unsigned int r = x + 0x7fffu + ((x >> 16) & 1u);
    return (unsigned short)(r >> 16);
}

// ---------------------------------------------------------------------------
// Kernel 1: Abf = bf16(L*X); Bbf = bf16((X@Wnet + bnet)*X)
// 32 rows/block, X tile staged in LDS, Wnet streamed (L2-resident, 64KB).
// ---------------------------------------------------------------------------
__global__ __launch_bounds__(256) void prep_kernel(
    const float* __restrict__ L, const float* __restrict__ X,
    const float* __restrict__ Wnet, const float* __restrict__ bnet,
    unsigned short* __restrict__ Abf, unsigned short* __restrict__ Bbf)
{
    __shared__ float Xs[32][128];   // 16 KB
    const int tid  = threadIdx.x;
    const int row0 = blockIdx.x * 32;

    #pragma unroll
    for (int i = 0; i < 16; ++i) {
        int idx = tid + i * 256;
        Xs[idx >> 7][idx & 127] = X[(size_t)row0 * 128 + idx];
    }
    __syncthreads();

    const int k  = tid & 127;   // output column
    const int rg = tid >> 7;    // 0/1: rows rg, rg+2, rg+4, ...
    float acc[16];
    #pragma unroll
    for (int t = 0; t < 16; ++t) acc[t] = 0.f;

    for (int c4 = 0; c4 < 128; c4 += 4) {
        float w0 = Wnet[(c4 + 0) * 128 + k];
        float w1 = Wnet[(c4 + 1) * 128 + k];
        float w2 = Wnet[(c4 + 2) * 128 + k];
        float w3 = Wnet[(c4 + 3) * 128 + k];
        #pragma unroll
        for (int t = 0; t < 16; ++t) {
            const float4 xv = *(const float4*)&Xs[2 * t + rg][c4]; // LDS broadcast
            acc[t] = fmaf(xv.x, w0, acc[t]);
            acc[t] = fmaf(xv.y, w1, acc[t]);
            acc[t] = fmaf(xv.z, w2, acc[t]);
            acc[t] = fmaf(xv.w, w3, acc[t]);
        }
    }

    const float bn = bnet[k];
    #pragma unroll
    for (int t = 0; t < 16; ++t) {
        int r = 2 * t + rg;
        float xv = Xs[r][k];
        size_t off = (size_t)(row0 + r) * 128 + k;
        float a = L[off] * xv;
        float b = (acc[t] + bn) * xv;
        Abf[off] = f2bf(a);
        Bbf[off] = f2bf(b);
    }
}

// ---------------------------------------------------------------------------
// Kernel 2: row norms of the bf16 A/B + zero the atomic accumulators.
// One wave per row (128 bf16 = 64 uints, one per lane).
// ---------------------------------------------------------------------------
__global__ __launch_bounds__(256) void norm_zero_kernel(
    const unsigned short* __restrict__ Abf, const unsigned short* __restrict__ Bbf,
    float* __restrict__ nA, float* __restrict__ nB,
    float* __restrict__ sumw, float* __restrict__ sumwy)
{
    const int wv   = threadIdx.x >> 6;
    const int lane = threadIdx.x & 63;
    const int row  = blockIdx.x * 4 + wv;

    const uint32_t ua = ((const uint32_t*)(Abf + (size_t)row * 128))[lane];
    const uint32_t ub = ((const uint32_t*)(Bbf + (size_t)row * 128))[lane];
    float a0 = __uint_as_float(ua << 16), a1 = __uint_as_float(ua & 0xffff0000u);
    float b0 = __uint_as_float(ub << 16), b1 = __uint_as_float(ub & 0xffff0000u);
    float sa = a0 * a0 + a1 * a1;
    float sb = b0 * b0 + b1 * b1;
    #pragma unroll
    for (int m = 1; m < 64; m <<= 1) {
        sa += __shfl_xor(sa, m, 64);
        sb += __shfl_xor(sb, m, 64);
    }
    if (lane == 0) {
        nA[row] = sa; nB[row] = sb;
        sumw[row] = 0.f; sumwy[row] = 0.f;
    }
}

// ---------------------------------------------------------------------------
// Kernel 3: fused pairwise kernel. Block = 256 thr (4 waves), i-tile = 128
// rows (32/wave), j-chunk = 512 cols (4 j-tiles of 128). Grid 64 x 16.
// S = A@B^T via mfma_f32_16x16x32_bf16; epilogue: w = exp(-sqrt(d2)),
// per-row sum(w), sum(w*Y) accumulated in regs, atomicAdd once per chunk.
// Fragment layouts (learn_hip verified): A/B operand m|n=lane&15,
// k=(lane>>4)*8+j ; C/D col=lane&15, row=(lane>>4)*4+reg.
// ---------------------------------------------------------------------------
__global__ __launch_bounds__(256) void pairwise_kernel(
    const unsigned short* __restrict__ Abf, const unsigned short* __restrict__ Bbf,
    const float* __restrict__ nA, const float* __restrict__ nB,
    const float* __restrict__ Y,
    float* __restrict__ sumw, float* __restrict__ sumwy)
{
    const int tid  = threadIdx.x;
    const int wv   = tid >> 6;
    const int lane = tid & 63;
    const int ln16 = lane & 15;
    const int quad = lane >> 4;
    const int i0     = blockIdx.x * 128;
    const int j0base = blockIdx.y * 512;

    // Persistent A fragments: wave wv owns rows [i0+wv*32, i0+wv*32+32)
    bf16x8 afrag[2][4];
    #pragma unroll
    for (int rt = 0; rt < 2; ++rt) {
        const unsigned short* ap =
            Abf + (size_t)(i0 + wv * 32 + rt * 16 + ln16) * 128 + quad * 8;
        #pragma unroll
        for (int ks = 0; ks < 4; ++ks)
            afrag[rt][ks] = *(const bf16x8*)(ap + ks * 32);
    }
    float na[2][4];
    #pragma unroll
    for (int rt = 0; rt < 2; ++rt)
        #pragma unroll
        for (int r = 0; r < 4; ++r)
            na[rt][r] = nA[i0 + wv * 32 + rt * 16 + quad * 4 + r];

    float accw[2][4], accwy[2][4];
    #pragma unroll
    for (int rt = 0; rt < 2; ++rt)
        #pragma unroll
        for (int r = 0; r < 4; ++r) { accw[rt][r] = 0.f; accwy[rt][r] = 0.f; }

    for (int jt = 0; jt < 4; ++jt) {
        const int j0 = j0base + jt * 128;
        #pragma unroll
        for (int ct = 0; ct < 8; ++ct) {
            const int jcol = j0 + ct * 16 + ln16;
            const unsigned short* bp = Bbf + (size_t)jcol * 128 + quad * 8;
            bf16x8 bfrag[4];
            #pragma unroll
            for (int ks = 0; ks < 4; ++ks)
                bfrag[ks] = *(const bf16x8*)(bp + ks * 32);
            const float nb = nB[jcol];
            const float yj = Y[jcol];
            #pragma unroll
            for (int rt = 0; rt < 2; ++rt) {
                f32x4 s = {0.f, 0.f, 0.f, 0.f};
                #pragma unroll
                for (int ks = 0; ks < 4; ++ks)
                    s = __builtin_amdgcn_mfma_f32_16x16x32_bf16(
                            afrag[rt][ks], bfrag[ks], s, 0, 0, 0);
                #pragma unroll
                for (int r = 0; r < 4; ++r) {
                    float d2   = fmaf(-2.f, s[r], na[rt][r] + nb);
                    d2         = fmaxf(d2, 1e-12f);
                    float dist = sqrtf(d2);
                    float w    = __expf(-dist);
                    accw[rt][r]  += w;
                    accwy[rt][r]  = fmaf(w, yj, accwy[rt][r]);
                }
            }
        }
    }

    // Reduce over the 16 column-lanes, then one atomicAdd per row.
    #pragma unroll
    for (int rt = 0; rt < 2; ++rt)
        #pragma unroll
        for (int r = 0; r < 4; ++r) {
            float w  = accw[rt][r];
            float wy = accwy[rt][r];
            #pragma unroll
            for (int m = 1; m < 16; m <<= 1) {
                w  += __shfl_xor(w,  m, 64);
                wy += __shfl_xor(wy, m, 64);
            }
            if (ln16 == 0) {
                int row = i0 + wv * 32 + rt * 16 + quad * 4 + r;
                atomicAdd(&sumw[row],  w);
                atomicAdd(&sumwy[row], wy);
            }
        }
}

// ---------------------------------------------------------------------------
// Kernel 4: pred = sumwy/sumw; loss = sum((Y-pred)^2) -> d_out[0]
// ---------------------------------------------------------------------------
__global__ __launch_bounds__(1024) void finish_kernel(
    const float* __restrict__ Y, const float* __restrict__ sumw,
    const float* __restrict__ sumwy, float* __restrict__ out)
{
    __shared__ float red[16];
    const int tid = threadIdx.x;
    float acc = 0.f;
    for (int i = tid; i < N_; i += 1024) {
        float pred = sumwy[i] / sumw[i];
        float e = Y[i] - pred;
        acc = fmaf(e, e, acc);
    }
    #pragma unroll
    for (int m = 1; m < 64; m <<= 1) acc += __shfl_xor(acc, m, 64);
    if ((tid & 63) == 0) red[tid >> 6] = acc;
    __syncthreads();
    if (tid < 64) {
        float v = (tid < 16) ? red[tid] : 0.f;
        #pragma unroll
        for (int m = 1; m < 16; m <<= 1) v += __shfl_xor(v, m, 64);
        if (tid == 0) out[0] = v;
    }
}

// ---------------------------------------------------------------------------
extern "C" void kernel_launch(void* const* d_in, const int* in_sizes, int n_in,
                              void* d_out, int out_size, void* d_ws, size_t ws_size,
                              hipStream_t stream)
{
    const float* L    = (const float*)d_in[0];
    const float* X    = (const float*)d_in[1];
    const float* Y    = (const float*)d_in[2];
    const float* Wnet = (const float*)d_in[3];
    const float* bnet = (const float*)d_in[4];
    float* out = (float*)d_out;

    // workspace layout (4.125 MB needed):
    //   Abf 2MB | Bbf 2MB | nA 32KB | nB 32KB | sumw 32KB | sumwy 32KB
    char* ws = (char*)d_ws;
    unsigned short* Abf = (unsigned short*)(ws);
    unsigned short* Bbf = (unsigned short*)(ws + (size_t)2 * 1024 * 1024);
    float* nA    = (float*)(ws + (size_t)4 * 1024 * 1024);
    float* nB    = (float*)(ws + (size_t)4 * 1024 * 1024 + 32 * 1024);
    float* sumw  = (float*)(ws + (size_t)4 * 1024 * 1024 + 64 * 1024);
    float* sumwy = (float*)(ws + (size_t)4 * 1024 * 1024 + 96 * 1024);

    prep_kernel<<<N_ / 32, 256, 0, stream>>>(L, X, Wnet, bnet, Abf, Bbf);
    norm_zero_kernel<<<N_ / 4, 256, 0, stream>>>(Abf, Bbf, nA, nB, sumw, sumwy);
    pairwise_kernel<<<dim3(N_ / 128, 16), 256, 0, stream>>>(Abf, Bbf, nA, nB, Y,
                                                            sumw, sumwy);
    finish_kernel<<<1, 1024, 0, stream>>>(Y, sumw, sumwy, out);
}

// Round 2
// 105.609 us; speedup vs baseline: 1.5292x; 1.5292x over previous
//
#include <hip/hip_runtime.h>
#include <hip/hip_bf16.h>
#include <cstdint>

// adknnLoss: N=8192, M=128.
//   A = L*X; B = (X@Wnet + bnet)*X
//   dist[i,j] = ||A_i - B_j||; drum = exp(-dist)
//   pred = (drum@Y)/drum.sum(1); loss = sum((Y-pred)^2)
//
// Round 2: swizzled MFMA-fragment layout (lane-contiguous), LDS-staged B
// tiles via global_load_lds_dwordx4 (shared across the block's 4 waves),
// raw v_sqrt/v_exp with (log2 e)^2 folded into the norms:
//   w = exp(-dist) = 2^(-sqrt(K2*d2)),  K2 = (log2 e)^2
//   K2*d2 = (K2*na) + (K2*nb) - (2*K2)*s
// Norms computed from bf16-rounded vectors -> d2 consistent (>= ~0).

#define N_ 8192
#define M_ 128
#define K2_ 2.0813689810056077f      // (log2 e)^2
#define NEG2K2_ -4.1627379620112154f // -2*(log2 e)^2

typedef __bf16 bf16x8 __attribute__((ext_vector_type(8)));
typedef float  f32x4  __attribute__((ext_vector_type(4)));

__device__ __forceinline__ unsigned short f2bf(float f) {
    unsigned int x = __float_as_uint(f);
    unsigned int r = x + 0x7fffu + ((x >> 16) & 1u);
    return (unsigned short)(r >> 16);
}

__device__ __forceinline__ void async_cp16(const void* g, void* l) {
    __builtin_amdgcn_global_load_lds(
        (const __attribute__((address_space(1))) void*)g,
        (__attribute__((address_space(3))) void*)l, 16, 0, 0);
}

// Swizzled fragment layout (both A and B operands of mfma_f32_16x16x32_bf16):
//   elem_off(row,k) = (row>>4)*2048 + (k>>5)*512 + ((k>>3)&3)*128 + (row&15)*8 + (k&7)
// A wave's fragment load for (group g, ks) is then: base + g*2048 + ks*512 + lane*8
// i.e. lane-contiguous 16B/lane (1 KB per wave-load).

// ---------------------------------------------------------------------------
// prep: Asw = swz(bf16(L*X)); Bsw = swz(bf16((X@Wnet+bnet)*X));
//       naS = K2*||a||^2; nbY = (K2*||b||^2, Y); zero sumw/sumwy.
// 512 blocks x 256 thr; 16 rows/block (one swizzle group). thread = (rr,k4):
// rows rr*2, rr*2+1; k = 4*k4..4*k4+3.
// ---------------------------------------------------------------------------
__global__ __launch_bounds__(256) void prep_kernel(
    const float* __restrict__ L, const float* __restrict__ X,
    const float* __restrict__ Y, const float* __restrict__ Wnet,
    const float* __restrict__ bnet,
    unsigned short* __restrict__ Asw, unsigned short* __restrict__ Bsw,
    float* __restrict__ naS, float2* __restrict__ nbY,
    float* __restrict__ sumw, float* __restrict__ sumwy)
{
    __shared__ float Xs[16][128];  // 8 KB
    const int tid  = threadIdx.x;
    const int row0 = blockIdx.x * 16;
    const int k4   = tid & 31;
    const int rr   = tid >> 5;

    #pragma unroll
    for (int i = 0; i < 2; ++i)
        ((float4*)Xs)[tid + i * 256] =
            ((const float4*)(X + (size_t)row0 * 128))[tid + i * 256];
    __syncthreads();

    float acc0[4] = {0.f, 0.f, 0.f, 0.f};
    float acc1[4] = {0.f, 0.f, 0.f, 0.f};
    const int r0 = rr * 2, r1 = rr * 2 + 1;
    #pragma unroll 4
    for (int c = 0; c < 128; ++c) {
        float4 w4 = *(const float4*)(Wnet + c * 128 + k4 * 4);
        float x0 = Xs[r0][c], x1 = Xs[r1][c];
        acc0[0] = fmaf(x0, w4.x, acc0[0]); acc1[0] = fmaf(x1, w4.x, acc1[0]);
        acc0[1] = fmaf(x0, w4.y, acc0[1]); acc1[1] = fmaf(x1, w4.y, acc1[1]);
        acc0[2] = fmaf(x0, w4.z, acc0[2]); acc1[2] = fmaf(x1, w4.z, acc1[2]);
        acc0[3] = fmaf(x0, w4.w, acc0[3]); acc1[3] = fmaf(x1, w4.w, acc1[3]);
    }

    const float4 bn4 = *(const float4*)(bnet + k4 * 4);
    float napart[2], nbpart[2];
    #pragma unroll
    for (int j = 0; j < 2; ++j) {
        const int ln  = rr * 2 + j;
        const int row = row0 + ln;
        const float* acc = j ? acc1 : acc0;
        const float4 xv = *(const float4*)(&Xs[ln][k4 * 4]);
        const float4 l4 = *(const float4*)(L + (size_t)row * 128 + k4 * 4);
        unsigned short apk[4], bpk[4];
        float nA_ = 0.f, nB_ = 0.f;
        const float xe[4] = {xv.x, xv.y, xv.z, xv.w};
        const float le[4] = {l4.x, l4.y, l4.z, l4.w};
        const float be[4] = {bn4.x, bn4.y, bn4.z, bn4.w};
        #pragma unroll
        for (int e = 0; e < 4; ++e) {
            float a = le[e] * xe[e];
            float b = (acc[e] + be[e]) * xe[e];
            unsigned short ua = f2bf(a), ub = f2bf(b);
            apk[e] = ua; bpk[e] = ub;
            float af = __uint_as_float((unsigned)ua << 16);
            float bf = __uint_as_float((unsigned)ub << 16);
            nA_ = fmaf(af, af, nA_);
            nB_ = fmaf(bf, bf, nB_);
        }
        napart[j] = nA_; nbpart[j] = nB_;
        size_t off = (size_t)blockIdx.x * 2048 + (size_t)(k4 >> 3) * 512
                   + (size_t)((k4 >> 1) & 3) * 128 + (size_t)ln * 8 + (k4 & 1) * 4;
        uint2 pa = make_uint2((unsigned)apk[0] | ((unsigned)apk[1] << 16),
                              (unsigned)apk[2] | ((unsigned)apk[3] << 16));
        uint2 pb = make_uint2((unsigned)bpk[0] | ((unsigned)bpk[1] << 16),
                              (unsigned)bpk[2] | ((unsigned)bpk[3] << 16));
        *(uint2*)(Asw + off) = pa;
        *(uint2*)(Bsw + off) = pb;
    }

    // reduce norms over the 32 k4-lanes (stay within 32-lane halves)
    #pragma unroll
    for (int m = 1; m <= 16; m <<= 1) {
        napart[0] += __shfl_xor(napart[0], m, 64);
        napart[1] += __shfl_xor(napart[1], m, 64);
        nbpart[0] += __shfl_xor(nbpart[0], m, 64);
        nbpart[1] += __shfl_xor(nbpart[1], m, 64);
    }
    if (k4 == 0) {
        #pragma unroll
        for (int j = 0; j < 2; ++j) {
            int row = row0 + rr * 2 + j;
            naS[row] = K2_ * napart[j];
            nbY[row] = make_float2(K2_ * nbpart[j], Y[row]);
        }
    }
    if (tid < 16) sumw[row0 + tid] = 0.f;
    else if (tid < 32) sumwy[row0 + tid - 16] = 0.f;
}

// ---------------------------------------------------------------------------
// pairwise: grid (64, 16). Block: 4 waves, i-tile 128 rows (32/wave),
// j-chunk 512 cols = 4 jt-tiles of 128 cols (8 groups of 16).
// B jt-tile (32 KB) staged into LDS via global_load_lds_dwordx4, shared by
// all 4 waves. nbY for the chunk (4 KB) staged once.
// ---------------------------------------------------------------------------
__global__ __launch_bounds__(256) void pairwise_kernel(
    const unsigned short* __restrict__ Asw, const unsigned short* __restrict__ Bsw,
    const float* __restrict__ naS, const float2* __restrict__ nbY,
    float* __restrict__ sumw, float* __restrict__ sumwy)
{
    __shared__ __align__(16) unsigned short ldsB[16384];  // 32 KB, 8 groups
    __shared__ __align__(16) float2 ldsNbY[512];          // 4 KB

    const int tid  = threadIdx.x;
    const int wv   = tid >> 6;
    const int lane = tid & 63;
    const int ln16 = lane & 15;
    const int quad = lane >> 4;
    const int i0   = blockIdx.x * 128;
    const int j0   = blockIdx.y * 512;

    // stage nbY chunk: 512 float2 = 256 float4, one per thread
    ((float4*)ldsNbY)[tid] = ((const float4*)(nbY + j0))[tid];

    // persistent A fragments + scaled norms
    bf16x8 afrag[2][4];
    float  na[2][4];
    #pragma unroll
    for (int rt = 0; rt < 2; ++rt) {
        const int gA = (i0 >> 4) + wv * 2 + rt;
        const unsigned short* ap = Asw + (size_t)gA * 2048 + lane * 8;
        #pragma unroll
        for (int ks = 0; ks < 4; ++ks)
            afrag[rt][ks] = *(const bf16x8*)(ap + ks * 512);
        #pragma unroll
        for (int r = 0; r < 4; ++r)
            na[rt][r] = naS[gA * 16 + quad * 4 + r];
    }

    float accw[2][4], accwy[2][4];
    #pragma unroll
    for (int rt = 0; rt < 2; ++rt)
        #pragma unroll
        for (int r = 0; r < 4; ++r) { accw[rt][r] = 0.f; accwy[rt][r] = 0.f; }

    for (int jt = 0; jt < 4; ++jt) {
        // stage 8 B-groups (32 KB); wave wv covers 8 KB as 8 x 1KB wave-loads
        {
            const unsigned short* gsrc = Bsw + (size_t)(j0 >> 4) * 2048
                                       + (size_t)jt * 16384 + wv * 4096 + lane * 8;
            unsigned short* ldst = ldsB + wv * 4096;  // wave-uniform base
            #pragma unroll
            for (int i = 0; i < 8; ++i)
                async_cp16(gsrc + i * 512, ldst + i * 512);
        }
        __syncthreads();

        #pragma unroll 2
        for (int ct = 0; ct < 8; ++ct) {
            bf16x8 bfrag[4];
            const unsigned short* bp = ldsB + ct * 2048 + lane * 8;
            #pragma unroll
            for (int ks = 0; ks < 4; ++ks)
                bfrag[ks] = *(const bf16x8*)(bp + ks * 512);
            const float2 nv = ldsNbY[jt * 128 + ct * 16 + ln16];

            #pragma unroll
            for (int rt = 0; rt < 2; ++rt) {
                f32x4 s = {0.f, 0.f, 0.f, 0.f};
                #pragma unroll
                for (int ks = 0; ks < 4; ++ks)
                    s = __builtin_amdgcn_mfma_f32_16x16x32_bf16(
                            afrag[rt][ks], bfrag[ks], s, 0, 0, 0);
                #pragma unroll
                for (int r = 0; r < 4; ++r) {
                    float d2 = fmaf(NEG2K2_, s[r], na[rt][r] + nv.x);
                    d2 = fmaxf(d2, 0.f);
                    float w = __builtin_amdgcn_exp2f(-__builtin_amdgcn_sqrtf(d2));
                    accw[rt][r] += w;
                    accwy[rt][r] = fmaf(w, nv.y, accwy[rt][r]);
                }
            }
        }
        __syncthreads();
    }

    // reduce over the 16 column-lanes, one atomic per row
    #pragma unroll
    for (int rt = 0; rt < 2; ++rt)
        #pragma unroll
        for (int r = 0; r < 4; ++r) {
            float w  = accw[rt][r];
            float wy = accwy[rt][r];
            #pragma unroll
            for (int m = 1; m <= 8; m <<= 1) {
                w  += __shfl_xor(w,  m, 64);
                wy += __shfl_xor(wy, m, 64);
            }
            if (ln16 == 0) {
                int row = i0 + wv * 32 + rt * 16 + quad * 4 + r;
                atomicAdd(&sumw[row],  w);
                atomicAdd(&sumwy[row], wy);
            }
        }
}

// ---------------------------------------------------------------------------
__global__ __launch_bounds__(1024) void finish_kernel(
    const float* __restrict__ Y, const float* __restrict__ sumw,
    const float* __restrict__ sumwy, float* __restrict__ out)
{
    __shared__ float red[16];
    const int tid = threadIdx.x;
    float acc = 0.f;
    #pragma unroll
    for (int i = 0; i < 2; ++i) {
        int idx = tid + i * 1024;
        float4 w4  = ((const float4*)sumw)[idx];
        float4 wy4 = ((const float4*)sumwy)[idx];
        float4 y4  = ((const float4*)Y)[idx];
        const float we[4]  = {w4.x, w4.y, w4.z, w4.w};
        const float wye[4] = {wy4.x, wy4.y, wy4.z, wy4.w};
        const float ye[4]  = {y4.x, y4.y, y4.z, y4.w};
        #pragma unroll
        for (int e = 0; e < 4; ++e) {
            float pred = wye[e] * __builtin_amdgcn_rcpf(we[e]);
            float d = ye[e] - pred;
            acc = fmaf(d, d, acc);
        }
    }
    #pragma unroll
    for (int m = 1; m < 64; m <<= 1) acc += __shfl_xor(acc, m, 64);
    if ((tid & 63) == 0) red[tid >> 6] = acc;
    __syncthreads();
    if (tid < 64) {
        float v = (tid < 16) ? red[tid] : 0.f;
        #pragma unroll
        for (int m = 1; m < 16; m <<= 1) v += __shfl_xor(v, m, 64);
        if (tid == 0) out[0] = v;
    }
}

// ---------------------------------------------------------------------------
extern "C" void kernel_launch(void* const* d_in, const int* in_sizes, int n_in,
                              void* d_out, int out_size, void* d_ws, size_t ws_size,
                              hipStream_t stream)
{
    const float* L    = (const float*)d_in[0];
    const float* X    = (const float*)d_in[1];
    const float* Y    = (const float*)d_in[2];
    const float* Wnet = (const float*)d_in[3];
    const float* bnet = (const float*)d_in[4];
    float* out = (float*)d_out;

    // ws: Asw 2MB | Bsw 2MB | naS 32KB | nbY 64KB | sumw 32KB | sumwy 32KB
    char* ws = (char*)d_ws;
    unsigned short* Asw = (unsigned short*)(ws);
    unsigned short* Bsw = (unsigned short*)(ws + (size_t)2 * 1024 * 1024);
    float*  naS   = (float*) (ws + (size_t)4 * 1024 * 1024);
    float2* nbYp  = (float2*)(ws + (size_t)4 * 1024 * 1024 + 32 * 1024);
    float*  sumw  = (float*) (ws + (size_t)4 * 1024 * 1024 + 96 * 1024);
    float*  sumwy = (float*) (ws + (size_t)4 * 1024 * 1024 + 128 * 1024);

    prep_kernel<<<N_ / 16, 256, 0, stream>>>(L, X, Y, Wnet, bnet,
                                             Asw, Bsw, naS, nbYp, sumw, sumwy);
    pairwise_kernel<<<dim3(N_ / 128, 16), 256, 0, stream>>>(Asw, Bsw, naS, nbYp,
                                                            sumw, sumwy);
    finish_kernel<<<1, 1024, 0, stream>>>(Y, sumw, sumwy, out);
}

// Round 3
// 105.549 us; speedup vs baseline: 1.5300x; 1.0006x over previous
//
#include <hip/hip_runtime.h>
#include <hip/hip_bf16.h>
#include <cstdint>

// adknnLoss: N=8192, M=128.
//   A = L*X; B = (X@Wnet + bnet)*X
//   dist[i,j] = ||A_i - B_j||; drum = exp(-dist)
//   pred = (drum@Y)/drum.sum(1); loss = sum((Y-pred)^2)
//
// Round 3: pairwise goes LDS-free — B fragments load straight from L2
// (swizzled lane-contiguous layout), no barriers, independent waves.
// Prep stages Wnet in LDS (kills the serial L2-latency chain).
//   w = exp(-dist) = 2^(-sqrt(K2*d2)),  K2 = (log2 e)^2, folded into norms.

#define N_ 8192
#define M_ 128
#define K2_ 2.0813689810056077f      // (log2 e)^2
#define NEG2K2_ -4.1627379620112154f // -2*(log2 e)^2

typedef __bf16 bf16x8 __attribute__((ext_vector_type(8)));
typedef float  f32x4  __attribute__((ext_vector_type(4)));

__device__ __forceinline__ unsigned short f2bf(float f) {
    unsigned int x = __float_as_uint(f);
    unsigned int r = x + 0x7fffu + ((x >> 16) & 1u);
    return (unsigned short)(r >> 16);
}

// Swizzled fragment layout (A and B operands of mfma_f32_16x16x32_bf16):
//   elem_off(row,k) = (row>>4)*2048 + (k>>5)*512 + ((k>>3)&3)*128 + (row&15)*8 + (k&7)
// Wave fragment load for (group g, ks): base + g*2048 + ks*512 + lane*8
// -> lane-contiguous 16 B/lane global_load_dwordx4.

// ---------------------------------------------------------------------------
// prep: Asw = swz(bf16(L*X)); Bsw = swz(bf16((X@Wnet+bnet)*X));
//       naS = K2*||a||^2; nbY = (K2*||b||^2, Y); zero sumw/sumwy.
// 512 blocks x 256 thr; 16 rows/block. Wnet staged in LDS (64 KB).
// thread = (rr,k4): rows rr*2, rr*2+1; out cols 4*k4..4*k4+3.
// ---------------------------------------------------------------------------
__global__ __launch_bounds__(256) void prep_kernel(
    const float* __restrict__ L, const float* __restrict__ X,
    const float* __restrict__ Y, const float* __restrict__ Wnet,
    const float* __restrict__ bnet,
    unsigned short* __restrict__ Asw, unsigned short* __restrict__ Bsw,
    float* __restrict__ naS, float2* __restrict__ nbY,
    float* __restrict__ sumw, float* __restrict__ sumwy)
{
    __shared__ float Ws[128 * 128];  // 64 KB
    __shared__ float Xs[16][128];    // 8 KB
    const int tid  = threadIdx.x;
    const int row0 = blockIdx.x * 16;
    const int k4   = tid & 31;
    const int rr   = tid >> 5;

    #pragma unroll
    for (int i = 0; i < 16; ++i)
        ((float4*)Ws)[tid + i * 256] = ((const float4*)Wnet)[tid + i * 256];
    #pragma unroll
    for (int i = 0; i < 2; ++i)
        ((float4*)Xs)[tid + i * 256] =
            ((const float4*)(X + (size_t)row0 * 128))[tid + i * 256];
    __syncthreads();

    float acc0[4] = {0.f, 0.f, 0.f, 0.f};
    float acc1[4] = {0.f, 0.f, 0.f, 0.f};
    const int r0 = rr * 2, r1 = rr * 2 + 1;
    #pragma unroll 2
    for (int c4 = 0; c4 < 128; c4 += 4) {
        const float4 x0 = *(const float4*)&Xs[r0][c4];
        const float4 x1 = *(const float4*)&Xs[r1][c4];
        const float4 wc0 = *(const float4*)&Ws[(c4 + 0) * 128 + k4 * 4];
        const float4 wc1 = *(const float4*)&Ws[(c4 + 1) * 128 + k4 * 4];
        const float4 wc2 = *(const float4*)&Ws[(c4 + 2) * 128 + k4 * 4];
        const float4 wc3 = *(const float4*)&Ws[(c4 + 3) * 128 + k4 * 4];
        const float x0e[4] = {x0.x, x0.y, x0.z, x0.w};
        const float x1e[4] = {x1.x, x1.y, x1.z, x1.w};
        const float4 wce[4] = {wc0, wc1, wc2, wc3};
        #pragma unroll
        for (int c = 0; c < 4; ++c) {
            acc0[0] = fmaf(x0e[c], wce[c].x, acc0[0]);
            acc0[1] = fmaf(x0e[c], wce[c].y, acc0[1]);
            acc0[2] = fmaf(x0e[c], wce[c].z, acc0[2]);
            acc0[3] = fmaf(x0e[c], wce[c].w, acc0[3]);
            acc1[0] = fmaf(x1e[c], wce[c].x, acc1[0]);
            acc1[1] = fmaf(x1e[c], wce[c].y, acc1[1]);
            acc1[2] = fmaf(x1e[c], wce[c].z, acc1[2]);
            acc1[3] = fmaf(x1e[c], wce[c].w, acc1[3]);
        }
    }

    const float4 bn4 = *(const float4*)(bnet + k4 * 4);
    float napart[2], nbpart[2];
    #pragma unroll
    for (int j = 0; j < 2; ++j) {
        const int ln  = rr * 2 + j;
        const int row = row0 + ln;
        const float* acc = j ? acc1 : acc0;
        const float4 xv = *(const float4*)(&Xs[ln][k4 * 4]);
        const float4 l4 = *(const float4*)(L + (size_t)row * 128 + k4 * 4);
        unsigned short apk[4], bpk[4];
        float nA_ = 0.f, nB_ = 0.f;
        const float xe[4] = {xv.x, xv.y, xv.z, xv.w};
        const float le[4] = {l4.x, l4.y, l4.z, l4.w};
        const float be[4] = {bn4.x, bn4.y, bn4.z, bn4.w};
        #pragma unroll
        for (int e = 0; e < 4; ++e) {
            float a = le[e] * xe[e];
            float b = (acc[e] + be[e]) * xe[e];
            unsigned short ua = f2bf(a), ub = f2bf(b);
            apk[e] = ua; bpk[e] = ub;
            float af = __uint_as_float((unsigned)ua << 16);
            float bf = __uint_as_float((unsigned)ub << 16);
            nA_ = fmaf(af, af, nA_);
            nB_ = fmaf(bf, bf, nB_);
        }
        napart[j] = nA_; nbpart[j] = nB_;
        size_t off = (size_t)blockIdx.x * 2048 + (size_t)(k4 >> 3) * 512
                   + (size_t)((k4 >> 1) & 3) * 128 + (size_t)ln * 8 + (k4 & 1) * 4;
        uint2 pa = make_uint2((unsigned)apk[0] | ((unsigned)apk[1] << 16),
                              (unsigned)apk[2] | ((unsigned)apk[3] << 16));
        uint2 pb = make_uint2((unsigned)bpk[0] | ((unsigned)bpk[1] << 16),
                              (unsigned)bpk[2] | ((unsigned)bpk[3] << 16));
        *(uint2*)(Asw + off) = pa;
        *(uint2*)(Bsw + off) = pb;
    }

    #pragma unroll
    for (int m = 1; m <= 16; m <<= 1) {
        napart[0] += __shfl_xor(napart[0], m, 64);
        napart[1] += __shfl_xor(napart[1], m, 64);
        nbpart[0] += __shfl_xor(nbpart[0], m, 64);
        nbpart[1] += __shfl_xor(nbpart[1], m, 64);
    }
    if (k4 == 0) {
        #pragma unroll
        for (int j = 0; j < 2; ++j) {
            int row = row0 + rr * 2 + j;
            naS[row] = K2_ * napart[j];
            nbY[row] = make_float2(K2_ * nbpart[j], Y[row]);
        }
    }
    if (tid < 16) sumw[row0 + tid] = 0.f;
    else if (tid < 32) sumwy[row0 + tid - 16] = 0.f;
}

// ---------------------------------------------------------------------------
// pairwise: grid (64, 16), 256 thr (4 waves). i-tile 128 rows (32/wave),
// j-chunk 512 cols = 32 groups of 16. NO LDS, no barriers: B fragments are
// lane-contiguous global_load_dwordx4 from the L2-resident swizzled Bsw;
// waves run fully independently (latency overlap across 16 waves/CU).
// ---------------------------------------------------------------------------
__global__ __launch_bounds__(256, 4) void pairwise_kernel(
    const unsigned short* __restrict__ Asw, const unsigned short* __restrict__ Bsw,
    const float* __restrict__ naS, const float2* __restrict__ nbY,
    float* __restrict__ sumw, float* __restrict__ sumwy)
{
    const int tid  = threadIdx.x;
    const int wv   = tid >> 6;
    const int lane = tid & 63;
    const int ln16 = lane & 15;
    const int quad = lane >> 4;
    const int i0   = blockIdx.x * 128;
    const int j0   = blockIdx.y * 512;

    // persistent A fragments + scaled norms
    bf16x8 afrag[2][4];
    float  na[2][4];
    #pragma unroll
    for (int rt = 0; rt < 2; ++rt) {
        const int gA = (i0 >> 4) + wv * 2 + rt;
        const unsigned short* ap = Asw + (size_t)gA * 2048 + lane * 8;
        #pragma unroll
        for (int ks = 0; ks < 4; ++ks)
            afrag[rt][ks] = *(const bf16x8*)(ap + ks * 512);
        #pragma unroll
        for (int r = 0; r < 4; ++r)
            na[rt][r] = naS[gA * 16 + quad * 4 + r];
    }

    float accw[2][4], accwy[2][4];
    #pragma unroll
    for (int rt = 0; rt < 2; ++rt)
        #pragma unroll
        for (int r = 0; r < 4; ++r) { accw[rt][r] = 0.f; accwy[rt][r] = 0.f; }

    const unsigned short* bbase = Bsw + (size_t)(j0 >> 4) * 2048 + lane * 8;
    const float2* nbbase = nbY + j0 + ln16;

    #pragma unroll 4
    for (int ct = 0; ct < 32; ++ct) {
        const unsigned short* bp = bbase + (size_t)ct * 2048;
        bf16x8 bfrag[4];
        #pragma unroll
        for (int ks = 0; ks < 4; ++ks)
            bfrag[ks] = *(const bf16x8*)(bp + ks * 512);
        const float2 nv = nbbase[ct * 16];

        #pragma unroll
        for (int rt = 0; rt < 2; ++rt) {
            f32x4 s = {0.f, 0.f, 0.f, 0.f};
            #pragma unroll
            for (int ks = 0; ks < 4; ++ks)
                s = __builtin_amdgcn_mfma_f32_16x16x32_bf16(
                        afrag[rt][ks], bfrag[ks], s, 0, 0, 0);
            #pragma unroll
            for (int r = 0; r < 4; ++r) {
                float d2 = fmaf(NEG2K2_, s[r], na[rt][r] + nv.x);
                d2 = fmaxf(d2, 0.f);
                float w = __builtin_amdgcn_exp2f(-__builtin_amdgcn_sqrtf(d2));
                accw[rt][r] += w;
                accwy[rt][r] = fmaf(w, nv.y, accwy[rt][r]);
            }
        }
    }

    // reduce over the 16 column-lanes, one atomic per row
    #pragma unroll
    for (int rt = 0; rt < 2; ++rt)
        #pragma unroll
        for (int r = 0; r < 4; ++r) {
            float w  = accw[rt][r];
            float wy = accwy[rt][r];
            #pragma unroll
            for (int m = 1; m <= 8; m <<= 1) {
                w  += __shfl_xor(w,  m, 64);
                wy += __shfl_xor(wy, m, 64);
            }
            if (ln16 == 0) {
                int row = i0 + wv * 32 + rt * 16 + quad * 4 + r;
                atomicAdd(&sumw[row],  w);
                atomicAdd(&sumwy[row], wy);
            }
        }
}

// ---------------------------------------------------------------------------
__global__ __launch_bounds__(1024) void finish_kernel(
    const float* __restrict__ Y, const float* __restrict__ sumw,
    const float* __restrict__ sumwy, float* __restrict__ out)
{
    __shared__ float red[16];
    const int tid = threadIdx.x;
    float acc = 0.f;
    #pragma unroll
    for (int i = 0; i < 2; ++i) {
        int idx = tid + i * 1024;
        float4 w4  = ((const float4*)sumw)[idx];
        float4 wy4 = ((const float4*)sumwy)[idx];
        float4 y4  = ((const float4*)Y)[idx];
        const float we[4]  = {w4.x, w4.y, w4.z, w4.w};
        const float wye[4] = {wy4.x, wy4.y, wy4.z, wy4.w};
        const float ye[4]  = {y4.x, y4.y, y4.z, y4.w};
        #pragma unroll
        for (int e = 0; e < 4; ++e) {
            float pred = wye[e] * __builtin_amdgcn_rcpf(we[e]);
            float d = ye[e] - pred;
            acc = fmaf(d, d, acc);
        }
    }
    #pragma unroll
    for (int m = 1; m < 64; m <<= 1) acc += __shfl_xor(acc, m, 64);
    if ((tid & 63) == 0) red[tid >> 6] = acc;
    __syncthreads();
    if (tid < 64) {
        float v = (tid < 16) ? red[tid] : 0.f;
        #pragma unroll
        for (int m = 1; m < 16; m <<= 1) v += __shfl_xor(v, m, 64);
        if (tid == 0) out[0] = v;
    }
}

// ---------------------------------------------------------------------------
extern "C" void kernel_launch(void* const* d_in, const int* in_sizes, int n_in,
                              void* d_out, int out_size, void* d_ws, size_t ws_size,
                              hipStream_t stream)
{
    const float* L    = (const float*)d_in[0];
    const float* X    = (const float*)d_in[1];
    const float* Y    = (const float*)d_in[2];
    const float* Wnet = (const float*)d_in[3];
    const float* bnet = (const float*)d_in[4];
    float* out = (float*)d_out;

    // ws: Asw 2MB | Bsw 2MB | naS 32KB | nbY 64KB | sumw 32KB | sumwy 32KB
    char* ws = (char*)d_ws;
    unsigned short* Asw = (unsigned short*)(ws);
    unsigned short* Bsw = (unsigned short*)(ws + (size_t)2 * 1024 * 1024);
    float*  naS   = (float*) (ws + (size_t)4 * 1024 * 1024);
    float2* nbYp  = (float2*)(ws + (size_t)4 * 1024 * 1024 + 32 * 1024);
    float*  sumw  = (float*) (ws + (size_t)4 * 1024 * 1024 + 96 * 1024);
    float*  sumwy = (float*) (ws + (size_t)4 * 1024 * 1024 + 128 * 1024);

    prep_kernel<<<N_ / 16, 256, 0, stream>>>(L, X, Y, Wnet, bnet,
                                             Asw, Bsw, naS, nbYp, sumw, sumwy);
    pairwise_kernel<<<dim3(N_ / 128, 16), 256, 0, stream>>>(Asw, Bsw, naS, nbYp,
                                                            sumw, sumwy);
    finish_kernel<<<1, 1024, 0, stream>>>(Y, sumw, sumwy, out);
}